// Round 3
// baseline (181.149 us; speedup 1.0000x reference)
//
#include <hip/hip_runtime.h>

typedef __bf16 bf16x8 __attribute__((ext_vector_type(8)));
typedef float f32x4 __attribute__((ext_vector_type(4)));
typedef unsigned int u32;

#define IN_STRIDE 88   // lds input row stride (elems); 176B = 16B-aligned rows
#define IN_ROWS   31   // 16 out rows + 14 halo + 1 row for kh=15 zero-pad slot (real data, A=0)
#define IN_COLS   80   // cols c0-8 .. c0+71 staged as 20 aligned float4 per row
#define SG  324        // lds_out oc-group stride (f32)
#define SH  20         // lds_out h stride (f32)
#define WAVE_OUT 1312  // per-wave lds_out size (f32)

__device__ __forceinline__ unsigned short f2bf(float f) {
    u32 u = __builtin_bit_cast(u32, f);
    return (unsigned short)((u + 0x7FFFu + ((u >> 16) & 1u)) >> 16);  // RNE
}
__device__ __forceinline__ int refl(int i) {  // reflect index into [0,512)
    return i < 0 ? -i : (i > 511 ? 1022 - i : i);
}

// One block: sample n, 16 output rows x 64 output cols, all 16 oc.
// Wave w owns cols [16w, 16w+16). K = 15x15 taps padded to 16x16=256 = 8 MFMA K-steps.
// k = 32*ks + 8*g + j  ->  kh = 4*g + (j>>1), kw = ks + 8*(j&1)   (g = lane>>4)
// => lane (hh,g) B-data = rows hh+4g..hh+4g+3, cols [16w, 16w+32) of staged tile,
//    loaded ONCE into W[4][16]; fragment depends only on e = t+ks+1 (23 diagonals).
template <int PASS>
__global__ __launch_bounds__(256) void dynconv(const float* __restrict__ x,
                                               const float* __restrict__ kern,
                                               float* __restrict__ out,
                                               float* __restrict__ bmax,
                                               const float* __restrict__ maxf) {
    __shared__ __align__(16) unsigned short lds_in[IN_ROWS * IN_STRIDE];
    __shared__ float wm[4];

    const int tid  = threadIdx.x;
    const int lane = tid & 63;
    const int wave = tid >> 6;
    const int n  = blockIdx.z;
    const int h0 = blockIdx.y * 16;
    const int c0 = blockIdx.x * 64;

    // ---- stage input tile (channel 0 only), reflect-padded, f32 -> bf16 ----
    // cols [c0-8, c0+72): 20 float4 slots per row; rows h0-7 .. h0+23 (reflected)
    const float* xs = x + (size_t)n * (16u * 512u * 512u);
    {
        const int cs = tid & 31;   // col slot (active < 20)
        const int r0 = tid >> 5;   // row 0..7, step 8
        if (cs < 20) {
            #pragma unroll
            for (int i = 0; i < 4; ++i) {
                const int rr = r0 + 8 * i;
                if (rr < IN_ROWS) {
                    const float* rowp = xs + refl(h0 - 7 + rr) * 512;
                    const int gc0 = c0 - 8 + 4 * cs;
                    float v0, v1, v2, v3;
                    if (gc0 >= 0 && gc0 <= 508) {           // aligned interior fast path
                        const float4 v = *(const float4*)(rowp + gc0);
                        v0 = v.x; v1 = v.y; v2 = v.z; v3 = v.w;
                    } else {                                // border reflect, scalar
                        v0 = rowp[refl(gc0)];
                        v1 = rowp[refl(gc0 + 1)];
                        v2 = rowp[refl(gc0 + 2)];
                        v3 = rowp[refl(gc0 + 3)];
                    }
                    const u32 lo = (u32)f2bf(v0) | ((u32)f2bf(v1) << 16);
                    const u32 hi = (u32)f2bf(v2) | ((u32)f2bf(v3) << 16);
                    *(uint2*)&lds_in[rr * IN_STRIDE + 4 * cs] = make_uint2(lo, hi);
                }
            }
        }
    }

    // ---- A fragments: kernel weights, zero-padded to 16x16 taps, in regs ----
    const int oca = lane & 15;
    const int g   = lane >> 4;
    bf16x8 afrag[8];
    const float* kp = kern + ((size_t)n * 16 + oca) * 225;
    #pragma unroll
    for (int ks = 0; ks < 8; ++ks) {
        #pragma unroll
        for (int j = 0; j < 8; ++j) {
            const int kh = 4 * g + (j >> 1);
            const int kw = ks + 8 * (j & 1);
            float v = 0.f;
            if (kh < 15 && kw < 15) v = kp[kh * 15 + kw];
            afrag[ks][j] = (__bf16)v;
        }
    }

    __syncthreads();

    // ---- load per-lane B window ONCE: 4 rows x 32 cols = 16 u32 words/row/4 ----
    const int hh = lane & 15;                 // B n-dim: output row offset
    u32 W[4][16];
    {
        const int rowb = hh + 4 * g;
        #pragma unroll
        for (int q = 0; q < 4; ++q) {
            const unsigned short* rp = &lds_in[(rowb + q) * IN_STRIDE + 16 * wave];
            const uint4 A0 = *(const uint4*)(rp);
            const uint4 A1 = *(const uint4*)(rp + 8);
            const uint4 A2 = *(const uint4*)(rp + 16);
            const uint4 A3 = *(const uint4*)(rp + 24);
            W[q][0]  = A0.x; W[q][1]  = A0.y; W[q][2]  = A0.z; W[q][3]  = A0.w;
            W[q][4]  = A1.x; W[q][5]  = A1.y; W[q][6]  = A1.z; W[q][7]  = A1.w;
            W[q][8]  = A2.x; W[q][9]  = A2.y; W[q][10] = A2.z; W[q][11] = A2.w;
            W[q][12] = A3.x; W[q][13] = A3.y; W[q][14] = A3.z; W[q][15] = A3.w;
        }
    }

    // ---- MFMA main loop: 23 diagonals e = t+ks+1, one fragment each ----
    f32x4 acc[16];
    #pragma unroll
    for (int t = 0; t < 16; ++t) acc[t] = f32x4{0.f, 0.f, 0.f, 0.f};

    #pragma unroll
    for (int e = 1; e <= 23; ++e) {
        const int a = e >> 1;
        uint4 dv;
        if (e & 1) {   // lo = elem e (hi16 of W[a]), hi = elem e+8 (hi16 of W[a+4])
            dv.x = (W[0][a] >> 16) | (W[0][a + 4] & 0xffff0000u);
            dv.y = (W[1][a] >> 16) | (W[1][a + 4] & 0xffff0000u);
            dv.z = (W[2][a] >> 16) | (W[2][a + 4] & 0xffff0000u);
            dv.w = (W[3][a] >> 16) | (W[3][a + 4] & 0xffff0000u);
        } else {       // lo = elem e (lo16 of W[a]), hi = elem e+8 (lo16 of W[a+4])
            dv.x = (W[0][a] & 0xffffu) | (W[0][a + 4] << 16);
            dv.y = (W[1][a] & 0xffffu) | (W[1][a + 4] << 16);
            dv.z = (W[2][a] & 0xffffu) | (W[2][a + 4] << 16);
            dv.w = (W[3][a] & 0xffffu) | (W[3][a + 4] << 16);
        }
        const bf16x8 bfrag = __builtin_bit_cast(bf16x8, dv);
        #pragma unroll
        for (int ks = 0; ks < 8; ++ks) {
            const int t = e - 1 - ks;
            if (t >= 0 && t < 16)
                acc[t] = __builtin_amdgcn_mfma_f32_16x16x32_bf16(
                    afrag[ks], bfrag, acc[t], 0, 0, 0);
        }
    }

    if constexpr (PASS == 0) {
        // ---- per-block max -> one plain store (no atomics) ----
        float m = -3.4e38f;
        #pragma unroll
        for (int t = 0; t < 16; ++t)
            #pragma unroll
            for (int r = 0; r < 4; ++r) m = fmaxf(m, acc[t][r]);
        #pragma unroll
        for (int off = 32; off > 0; off >>= 1) m = fmaxf(m, __shfl_xor(m, off, 64));
        if (lane == 0) wm[wave] = m;
        __syncthreads();
        if (tid == 0)
            bmax[n * 256 + blockIdx.y * 8 + blockIdx.x] =
                fmaxf(fmaxf(wm[0], wm[1]), fmaxf(wm[2], wm[3]));
    } else {
        // ---- scale + rearrange through per-wave LDS -> coalesced float4 stores ----
        __shared__ __align__(16) float lds_out[4 * WAVE_OUT];
        const float scale = 1.0f / maxf[n];
        float* ow = &lds_out[wave * WAVE_OUT];
        #pragma unroll
        for (int r = 0; r < 4; ++r) {
            #pragma unroll
            for (int q = 0; q < 4; ++q) {
                f32x4 v;
                v[0] = acc[4 * q + 0][r] * scale;
                v[1] = acc[4 * q + 1][r] * scale;
                v[2] = acc[4 * q + 2][r] * scale;
                v[3] = acc[4 * q + 3][r] * scale;
                *(f32x4*)&ow[g * SG + hh * SH + 4 * q] = v;   // (oc-grp g, row hh, w 4q..)
            }
            const int hr = lane >> 2;
            const int c  = lane & 3;
            #pragma unroll
            for (int j = 0; j < 4; ++j) {                      // oc-group j
                f32x4 v = *(const f32x4*)&ow[j * SG + hr * SH + 4 * c];
                const int oc = 4 * j + r;
                size_t o = (((size_t)(oc * 16 + n)) * 512 + (size_t)(h0 + hr)) * 512
                           + (size_t)(c0 + wave * 16 + 4 * c);
                *(f32x4*)&out[o] = v;
            }
        }
    }
}

// 16 blocks: reduce 256 per-block maxima -> maxf[n]
__global__ __launch_bounds__(256) void reducemax(const float* __restrict__ bmax,
                                                 float* __restrict__ maxf) {
    const int n = blockIdx.x;
    float v = bmax[n * 256 + threadIdx.x];
    #pragma unroll
    for (int off = 32; off > 0; off >>= 1) v = fmaxf(v, __shfl_xor(v, off, 64));
    __shared__ float wm[4];
    if ((threadIdx.x & 63) == 0) wm[threadIdx.x >> 6] = v;
    __syncthreads();
    if (threadIdx.x == 0)
        maxf[n] = fmaxf(fmaxf(wm[0], wm[1]), fmaxf(wm[2], wm[3]));
}

extern "C" void kernel_launch(void* const* d_in, const int* in_sizes, int n_in,
                              void* d_out, int out_size, void* d_ws, size_t ws_size,
                              hipStream_t stream) {
    (void)in_sizes; (void)n_in; (void)out_size; (void)ws_size;
    const float* x  = (const float*)d_in[0];
    const float* k  = (const float*)d_in[1];
    float* out      = (float*)d_out;
    float* bmax     = (float*)d_ws;          // 16*256 floats
    float* maxf     = bmax + 16 * 256;       // 16 floats

    dim3 grid(8, 32, 16);   // (512/64 col-tiles, 512/16 row-tiles, 16 samples)
    dim3 block(256);
    dynconv<0><<<grid, block, 0, stream>>>(x, k, out, bmax, maxf);  // max pass
    reducemax<<<dim3(16), block, 0, stream>>>(bmax, maxf);          // 16 maxima
    dynconv<1><<<grid, block, 0, stream>>>(x, k, out, bmax, maxf);  // write pass
}

// Round 5
// 154.868 us; speedup vs baseline: 1.1697x; 1.1697x over previous
//
#include <hip/hip_runtime.h>
#include <hip/hip_cooperative_groups.h>

namespace cg = cooperative_groups;

typedef __bf16 bf16x8 __attribute__((ext_vector_type(8)));
typedef float f32x4 __attribute__((ext_vector_type(4)));
typedef unsigned int u32;

#define IN_STRIDE 152  // lds input row stride (elems); 304B = 16B-aligned rows
#define IN_ROWS   31   // 16 out rows + 14 halo + 1 row for kh=15 zero-pad slot
#define IN_SLOTS  36   // float4 col slots per row: cols [c0q-8, c0q+136) = 144
#define SG  324        // lds_out oc-group stride (f32)
#define SH  20         // lds_out h stride (f32)
#define WAVE_OUT 1312  // per-wave lds_out size (f32)

__device__ __forceinline__ unsigned short f2bf(float f) {
    u32 u = __builtin_bit_cast(u32, f);
    return (unsigned short)((u + 0x7FFFu + ((u >> 16) & 1u)) >> 16);  // RNE
}
__device__ __forceinline__ int refl(int i) {  // reflect index into [0,512)
    return i < 0 ? -i : (i > 511 ? 1022 - i : i);
}

// Block b: sample n = b>>5, rows h0 = (b&31)*16, all 512 cols (4 chunks of 128),
// all 16 oc. Wave w owns cols [16w,16w+16) of each 64-col subtile.
// K = 15x15 taps padded to 16x16 = 256 = 8 MFMA K-steps (r2 mapping, HW-validated):
// k = 32*ks + 8*g + j  ->  kh = 2*ks + (g>>1), kw = 8*(g&1) + j   (g = lane>>4)
// MODE 0: max pass only (writes partial[b]).  MODE 1: scale pass only (reads maxf).
// MODE 2: fused cooperative (phase A, grid sync, phase C).
template <int MODE>
__global__ __launch_bounds__(256, 2) void dynconv(const float* __restrict__ x,
                                                  const float* __restrict__ kern,
                                                  float* __restrict__ out,
                                                  float* __restrict__ partial,
                                                  const float* __restrict__ maxf) {
    __shared__ __align__(16) unsigned short lds_in[IN_ROWS * IN_STRIDE];  // 9424B
    __shared__ __align__(16) float lds_out[4 * WAVE_OUT];                 // 20992B
    __shared__ float wm[4];

    const int tid  = threadIdx.x;
    const int lane = tid & 63;
    const int wave = tid >> 6;
    const int b  = blockIdx.x;
    const int n  = b >> 5;
    const int h0 = (b & 31) * 16;

    const float* xs = x + (size_t)n * (16u * 512u * 512u);

    // ---- A fragments: kernel weights, zero-padded to 16x16 taps, loaded once ----
    const int oca = lane & 15;
    const int g   = lane >> 4;
    const int g1  = g & 1;
    const int g2  = g >> 1;
    bf16x8 afrag[8];
    {
        const float* kp = kern + ((size_t)n * 16 + oca) * 225;
        #pragma unroll
        for (int ks = 0; ks < 8; ++ks) {
            const int kh = 2 * ks + g2;
            #pragma unroll
            for (int j = 0; j < 8; ++j) {
                const int kwv = 8 * g1 + j;
                float v = 0.f;
                if (kh < 15 && kwv < 15) v = kp[kh * 15 + kwv];
                afrag[ks][j] = (__bf16)v;
            }
        }
    }

    const int hh = lane & 15;               // B n-dim: output row offset
    const int colbase0 = wave * 16 + g1 * 8;

    // ---- stage a 31 x 144 tile (cols c0q-8 .. c0q+135), reflect, f32->bf16 ----
    auto stage = [&](int c0q) {
        for (int idx = tid; idx < IN_ROWS * IN_SLOTS; idx += 256) {
            const int rr = idx / IN_SLOTS;
            const int cs = idx - rr * IN_SLOTS;
            const float* rowp = xs + refl(h0 - 7 + rr) * 512;
            const int gc0 = c0q - 8 + 4 * cs;
            float v0, v1, v2, v3;
            if (gc0 >= 0 && gc0 <= 508) {           // aligned interior fast path
                const float4 v = *(const float4*)(rowp + gc0);
                v0 = v.x; v1 = v.y; v2 = v.z; v3 = v.w;
            } else {                                // border reflect, scalar
                v0 = rowp[refl(gc0)];
                v1 = rowp[refl(gc0 + 1)];
                v2 = rowp[refl(gc0 + 2)];
                v3 = rowp[refl(gc0 + 3)];
            }
            const u32 lo = (u32)f2bf(v0) | ((u32)f2bf(v1) << 16);
            const u32 hi = (u32)f2bf(v2) | ((u32)f2bf(v3) << 16);
            *(uint2*)&lds_in[rr * IN_STRIDE + 4 * cs] = make_uint2(lo, hi);
        }
    };

    // ---- conv of one 16h x 64w subtile at col offset w0*64 within staged tile ----
    auto conv = [&](int w0, f32x4* acc) {
        #pragma unroll
        for (int t = 0; t < 16; ++t) acc[t] = f32x4{0.f, 0.f, 0.f, 0.f};
        const int colbase = w0 * 64 + colbase0;
        #pragma unroll
        for (int ks = 0; ks < 8; ++ks) {
            const int row = hh + 2 * ks + g2;
            const unsigned short* rp = &lds_in[row * IN_STRIDE + colbase];
            const uint4 R0 = *(const uint4*)(rp);
            const uint4 R1 = *(const uint4*)(rp + 8);
            const uint4 R2 = *(const uint4*)(rp + 16);
            const u32 E[12] = {R0.x, R0.y, R0.z, R0.w, R1.x, R1.y, R1.z, R1.w,
                               R2.x, R2.y, R2.z, R2.w};
            #pragma unroll
            for (int t = 0; t < 16; ++t) {   // window shift s = t+1 (stage at -8)
                const int s  = t + 1;
                const int xb = s >> 1;
                u32 d0, d1, d2, d3;
                if (s & 1) {
                    d0 = __builtin_amdgcn_alignbit(E[xb + 1], E[xb], 16);
                    d1 = __builtin_amdgcn_alignbit(E[xb + 2], E[xb + 1], 16);
                    d2 = __builtin_amdgcn_alignbit(E[xb + 3], E[xb + 2], 16);
                    d3 = __builtin_amdgcn_alignbit(E[xb + 4], E[xb + 3], 16);
                } else {
                    d0 = E[xb]; d1 = E[xb + 1]; d2 = E[xb + 2]; d3 = E[xb + 3];
                }
                uint4 dv; dv.x = d0; dv.y = d1; dv.z = d2; dv.w = d3;
                acc[t] = __builtin_amdgcn_mfma_f32_16x16x32_bf16(
                    afrag[ks], __builtin_bit_cast(bf16x8, dv), acc[t], 0, 0, 0);
            }
        }
    };

    // ================= phase A: conv, per-block max =================
    if constexpr (MODE != 1) {
        float m = -3.4e38f;
        #pragma unroll 1
        for (int cq = 0; cq < 4; ++cq) {
            __syncthreads();
            stage(cq * 128);
            __syncthreads();
            #pragma unroll 1
            for (int w0 = 0; w0 < 2; ++w0) {
                f32x4 acc[16];
                conv(w0, acc);
                #pragma unroll
                for (int t = 0; t < 16; ++t)
                    #pragma unroll
                    for (int r = 0; r < 4; ++r) m = fmaxf(m, acc[t][r]);
            }
        }
        #pragma unroll
        for (int off = 32; off > 0; off >>= 1) m = fmaxf(m, __shfl_xor(m, off, 64));
        if (lane == 0) wm[wave] = m;
        __syncthreads();
        if (tid == 0)
            __hip_atomic_store(&partial[b],
                               fmaxf(fmaxf(wm[0], wm[1]), fmaxf(wm[2], wm[3])),
                               __ATOMIC_RELAXED, __HIP_MEMORY_SCOPE_AGENT);
    }

    if constexpr (MODE == 0) return;

    float scale;
    if constexpr (MODE == 2) {
        cg::this_grid().sync();
        float pv = __hip_atomic_load(&partial[(n << 5) + (lane & 31)],
                                     __ATOMIC_RELAXED, __HIP_MEMORY_SCOPE_AGENT);
        #pragma unroll
        for (int off = 16; off > 0; off >>= 1) pv = fmaxf(pv, __shfl_xor(pv, off, 64));
        scale = 1.0f / pv;
    } else {
        scale = 1.0f / maxf[n];
    }

    // ================= phase C: recompute, scale, store =================
    #pragma unroll 1
    for (int ci = 0; ci < 4; ++ci) {
        const int cq = (MODE == 2) ? ((ci + 3) & 3) : ci;  // coop: tile 3 resident
        if (MODE != 2 || ci > 0) {
            __syncthreads();
            stage(cq * 128);
            __syncthreads();
        }
        #pragma unroll 1
        for (int w0 = 0; w0 < 2; ++w0) {
            f32x4 acc[16];
            conv(w0, acc);
            const int c0 = cq * 128 + w0 * 64;
            float* ow = &lds_out[wave * WAVE_OUT];
            #pragma unroll
            for (int r = 0; r < 4; ++r) {
                #pragma unroll
                for (int q = 0; q < 4; ++q) {
                    f32x4 v;
                    v[0] = acc[4 * q + 0][r] * scale;
                    v[1] = acc[4 * q + 1][r] * scale;
                    v[2] = acc[4 * q + 2][r] * scale;
                    v[3] = acc[4 * q + 3][r] * scale;
                    *(f32x4*)&ow[g * SG + hh * SH + 4 * q] = v;
                }
                const int hr = lane >> 2;
                const int c  = lane & 3;
                #pragma unroll
                for (int j = 0; j < 4; ++j) {
                    f32x4 v = *(const f32x4*)&ow[j * SG + hr * SH + 4 * c];
                    const int oc = 4 * j + r;
                    size_t o = (((size_t)(oc * 16 + n)) * 512 + (size_t)(h0 + hr)) * 512
                               + (size_t)(c0 + wave * 16 + 4 * c);
                    *(f32x4*)&out[o] = v;
                }
            }
        }
    }
}

// Fallback reduce: 16 blocks x 64 threads; maxf[n] = max of partial[n*32..n*32+31]
__global__ void reducemax(const float* __restrict__ partial, float* __restrict__ maxf) {
    const int n = blockIdx.x;
    float v = partial[n * 32 + (threadIdx.x & 31)];
    #pragma unroll
    for (int off = 16; off > 0; off >>= 1) v = fmaxf(v, __shfl_xor(v, off, 64));
    if (threadIdx.x == 0) maxf[n] = v;
}

extern "C" void kernel_launch(void* const* d_in, const int* in_sizes, int n_in,
                              void* d_out, int out_size, void* d_ws, size_t ws_size,
                              hipStream_t stream) {
    (void)in_sizes; (void)n_in; (void)out_size; (void)ws_size;
    const float* x  = (const float*)d_in[0];
    const float* k  = (const float*)d_in[1];
    float* out      = (float*)d_out;
    float* partial  = (float*)d_ws;          // 512 floats
    float* maxf     = partial + 512;         // 16 floats

    void* args[] = {(void*)&x, (void*)&k, (void*)&out, (void*)&partial, (void*)&maxf};
    // 512 blocks = 2/CU co-resident (30.4KB LDS/block, launch_bounds(256,2)).
    hipError_t err = hipLaunchCooperativeKernel((void*)dynconv<2>, dim3(512),
                                                dim3(256), args, 0, stream);
    if (err != hipSuccess) {
        // Fallback: known-good 3-launch structure (no grid sync needed).
        dynconv<0><<<dim3(512), dim3(256), 0, stream>>>(x, k, out, partial, maxf);
        reducemax<<<dim3(16), dim3(64), 0, stream>>>(partial, maxf);
        dynconv<1><<<dim3(512), dim3(256), 0, stream>>>(x, k, out, partial, maxf);
    }
}